// Round 13
// baseline (25.792 us; speedup 1.0000x reference)
//
#include <hip/hip_runtime.h>

#define BB 16
#define NN 6000
#define GG 512
#define WAVES 8
#define RPT 3
#define RPB (RPT * 64)   // 192 ROIs/block; grid.x = 32 -> 512 blocks = 2/CU

__device__ __forceinline__ int rfl(int v) { return __builtin_amdgcn_readfirstlane(v); }

__global__ __launch_bounds__(64 * WAVES) void det_kernel(
    const float4* __restrict__ rois,      // (B, N, 4)
    const int*    __restrict__ gt_ids,    // (B, G)
    const float4* __restrict__ gt_boxes,  // (B, G, 4)
    float*        __restrict__ out)       // [B*2*N maxes][B*N pos][B*N neg]
{
    __shared__ float4 s_box[GG + 8];          // [0,nc_eff) nc, [nc_eff, nc_eff+cc_eff) crowd
    __shared__ float4 s_area4[(GG + 8) / 4];
    __shared__ float  s_ncm[WAVES][RPB];
    __shared__ float  s_cm[WAVES][RPB];
    __shared__ float  s_val[RPB];
    __shared__ int    s_wn[WAVES], s_wc[WAVES];   // per-wave popcounts
    float* s_area = (float*)s_area4;

    const int b    = blockIdx.y;
    const int tid  = threadIdx.x;
    const int wave = tid >> 6;
    const int lane = tid & 63;

    // ---- issue all global loads first ----
    const int nbase = blockIdx.x * RPB;
    float4 r[RPT];
    float  rs[RPT];
    #pragma unroll
    for (int i = 0; i < RPT; ++i) {
        int n = nbase + i * 64 + lane;
        r[i] = (n < NN) ? rois[b * NN + n] : make_float4(0.f, 0.f, 0.f, 0.f);
    }
    const float4 box = gt_boxes[b * GG + tid];    // one GT per thread (512 == GG)
    const int    id  = gt_ids[b * GG + tid];

    #pragma unroll
    for (int i = 0; i < RPT; ++i) {
        rs[i] = (r[i].z - r[i].x) * (r[i].w - r[i].y) + 1e-8f;
        if (wave == 0)
            s_val[i * 64 + lane] =
                ((fabsf(r[i].x) + fabsf(r[i].y) + fabsf(r[i].z) + fabsf(r[i].w)) > 0.f) ? 1.f : 0.f;
    }

    // ---- ballot compaction, atomic-free (per-wave prefix) ----
    const float asum = fabsf(box.x) + fabsf(box.y) + fabsf(box.z) + fabsf(box.w);
    const bool pn = (asum > 0.0f) && (id > 0);
    const bool pc = (asum > 0.0f) && (id < 0);
    const unsigned long long mn = __ballot(pn);
    const unsigned long long mc = __ballot(pc);
    if (lane == 0) { s_wn[wave] = __popcll(mn); s_wc[wave] = __popcll(mc); }
    __syncthreads();

    int bn = 0, bc = 0, ncnt = 0, ccnt = 0;
    #pragma unroll
    for (int w = 0; w < WAVES; ++w) {
        int pw = s_wn[w], cw = s_wc[w];
        if (w < wave) { bn += pw; bc += cw; }
        ncnt += pw; ccnt += cw;
    }
    const int nc_eff = (ncnt + 3) & ~3;           // nc list [0, nc_eff), x4
    const int cc_eff = (ccnt + 3) & ~3;           // crowd list [nc_eff, nc_eff+cc_eff), x4

    {
        const unsigned long long lt = (1ULL << lane) - 1ULL;
        if (pn) {
            int idx = bn + __popcll(mn & lt);
            s_box[idx]  = box;
            s_area[idx] = (box.z - box.x) * (box.w - box.y);
        }
        if (pc) {
            int idx = nc_eff + bc + __popcll(mc & lt);
            s_box[idx]  = box;
            s_area[idx] = (box.z - box.x) * (box.w - box.y);
        }
        // zero-fill pad slots (zero box => t=0, harmless for max)
        const float4 z = make_float4(0.f, 0.f, 0.f, 0.f);
        if (tid < 4) {
            int i = ncnt + tid;
            if (i < nc_eff) { s_box[i] = z; s_area[i] = 0.f; }
        } else if (tid < 8) {
            int i = nc_eff + ccnt + (tid - 4);
            if (i < nc_eff + cc_eff) { s_box[i] = z; s_area[i] = 0.f; }
        }
    }
    __syncthreads();

    // t = inter * rcp(rarea + garea + eps)  (monotone in IoU)
    auto tval = [](const float4& rr, float rsum, const float4& g4, float ga) -> float {
        float dy = fminf(rr.z, g4.z) - fmaxf(rr.x, g4.x);
        float dx = fminf(rr.w, g4.w) - fmaxf(rr.y, g4.y);
        float inter = fmaxf(fmaxf(dy, 0.f) * dx, 0.f);
        return inter * __builtin_amdgcn_rcpf(rsum + ga);
    };

    float anc[RPT] = {0.f, 0.f, 0.f};
    float ac[RPT]  = {0.f, 0.f, 0.f};

    const int ngrn  = rfl(nc_eff >> 2);                 // nc groups
    const int totgr = rfl((nc_eff + cc_eff) >> 2);      // total groups (contiguous)

    // ---- single strided, software-pipelined loop over ALL groups ----
    if (wave < totgr) {
        int u = wave;
        float4 nb0 = s_box[4 * u + 0];
        float4 nb1 = s_box[4 * u + 1];
        float4 nb2 = s_box[4 * u + 2];
        float4 nb3 = s_box[4 * u + 3];
        float4 na  = s_area4[u];
        for (; u < totgr; u += WAVES) {
            const float4 cb0 = nb0, cb1 = nb1, cb2 = nb2, cb3 = nb3, ca = na;
            const int un = (u + WAVES < totgr) ? u + WAVES : u;   // wrap: self (unused)
            nb0 = s_box[4 * un + 0];
            nb1 = s_box[4 * un + 1];
            nb2 = s_box[4 * un + 2];
            nb3 = s_box[4 * un + 3];
            na  = s_area4[un];
            const int isnc = rfl((int)(u < ngrn));      // wave-uniform -> scalar branch
            if (isnc) {
                #pragma unroll
                for (int i = 0; i < RPT; ++i) {
                    float t0 = tval(r[i], rs[i], cb0, ca.x);
                    float t1 = tval(r[i], rs[i], cb1, ca.y);
                    float t2 = tval(r[i], rs[i], cb2, ca.z);
                    float t3 = tval(r[i], rs[i], cb3, ca.w);
                    float m  = fmaxf(fmaxf(t0, t1), t2);          // v_max3
                    anc[i]   = fmaxf(fmaxf(m, t3), anc[i]);       // v_max3
                }
            } else {
                #pragma unroll
                for (int i = 0; i < RPT; ++i) {
                    float t0 = tval(r[i], rs[i], cb0, ca.x);
                    float t1 = tval(r[i], rs[i], cb1, ca.y);
                    float t2 = tval(r[i], rs[i], cb2, ca.z);
                    float t3 = tval(r[i], rs[i], cb3, ca.w);
                    float m  = fmaxf(fmaxf(t0, t1), t2);
                    ac[i]    = fmaxf(fmaxf(m, t3), ac[i]);
                }
            }
        }
    }

    #pragma unroll
    for (int i = 0; i < RPT; ++i) {
        s_ncm[wave][i * 64 + lane] = anc[i];
        s_cm[wave][i * 64 + lane]  = ac[i];
    }
    __syncthreads();

    // ---- reduce across waves; threads 0..RPB-1 own one ROI slot each ----
    if (tid < RPB) {
        const int n = nbase + tid;
        if (n < NN) {
            float a = s_ncm[0][tid], c = s_cm[0][tid];
            #pragma unroll
            for (int w = 1; w < WAVES; ++w) {
                a = fmaxf(a, s_ncm[w][tid]);
                c = fmaxf(c, s_cm[w][tid]);
            }
            const float vr = s_val[tid];           // 1.0 or 0.0
            a *= vr;
            c *= vr;
            // t -> iou: iou = t/(1-t); t in [0, 0.5] so well-conditioned
            const float nc_max = a * __builtin_amdgcn_rcpf(1.f - a);
            const float c_max  = c * __builtin_amdgcn_rcpf(1.f - c);

            out[b * 2 * NN + n]      = nc_max;     // iou_maxes (B,2,N) ch0
            out[b * 2 * NN + NN + n] = c_max;      // iou_maxes (B,2,N) ch1
            const float pos = (vr > 0.f && nc_max >= 0.5f) ? 1.0f : 0.0f;
            const float neg = (vr > 0.f && nc_max < 0.5f && c_max < 0.001f) ? 1.0f : 0.0f;
            out[BB * 2 * NN + b * NN + n]           = pos;
            out[BB * 2 * NN + BB * NN + b * NN + n] = neg;
        }
    }
}

extern "C" void kernel_launch(void* const* d_in, const int* in_sizes, int n_in,
                              void* d_out, int out_size, void* d_ws, size_t ws_size,
                              hipStream_t stream) {
    const float4* rois     = (const float4*)d_in[0];
    const int*    gt_ids   = (const int*)d_in[1];
    const float4* gt_boxes = (const float4*)d_in[2];
    float*        out      = (float*)d_out;

    dim3 grid((NN + RPB - 1) / RPB, BB);   // 32 x 16 = 512 blocks = exactly 2/CU
    det_kernel<<<grid, 64 * WAVES, 0, stream>>>(rois, gt_ids, gt_boxes, out);
}

// Round 14
// 25.077 us; speedup vs baseline: 1.0285x; 1.0285x over previous
//
#include <hip/hip_runtime.h>

#define BB 16
#define NN 6000
#define GG 512
#define WAVES 8
#define RPT 2
#define RPB (RPT * 64)   // 128 ROIs/block; grid.x = 47 -> 752 blocks

__device__ __forceinline__ int rfl(int v) { return __builtin_amdgcn_readfirstlane(v); }

__global__ __launch_bounds__(64 * WAVES, 8) void det_kernel(   // 8 waves/EU -> VGPR<=64, 32 waves/CU
    const float4* __restrict__ rois,      // (B, N, 4)
    const int*    __restrict__ gt_ids,    // (B, G)
    const float4* __restrict__ gt_boxes,  // (B, G, 4)
    float*        __restrict__ out)       // [B*2*N maxes][B*N pos][B*N neg]
{
    __shared__ float4 s_box[GG];             // nc from front, crowd from back
    __shared__ float4 s_area4[GG / 4];
    __shared__ float  s_ncm[WAVES][RPB];
    __shared__ float  s_cm[WAVES][RPB];
    __shared__ int    s_wn[WAVES], s_wc[WAVES];   // per-wave popcounts
    float* s_area = (float*)s_area4;

    const int b    = blockIdx.y;
    const int tid  = threadIdx.x;
    const int wave = tid >> 6;
    const int lane = tid & 63;

    // ---- issue all global loads first ----
    const int nbase = blockIdx.x * RPB;
    float4 r[RPT];
    float  rs[RPT];
    #pragma unroll
    for (int i = 0; i < RPT; ++i) {
        int n = nbase + i * 64 + lane;
        r[i] = (n < NN) ? rois[b * NN + n] : make_float4(0.f, 0.f, 0.f, 0.f);
    }
    const float4 box = gt_boxes[b * GG + tid];    // one GT per thread (512 == GG)
    const int    id  = gt_ids[b * GG + tid];

    #pragma unroll
    for (int i = 0; i < RPT; ++i)
        rs[i] = (r[i].z - r[i].x) * (r[i].w - r[i].y) + 1e-8f;

    // ---- ballot compaction, atomic-free (per-wave prefix) ----
    const float asum = fabsf(box.x) + fabsf(box.y) + fabsf(box.z) + fabsf(box.w);
    const bool pn = (asum > 0.0f) && (id > 0);
    const bool pc = (asum > 0.0f) && (id < 0);
    const unsigned long long mn = __ballot(pn);
    const unsigned long long mc = __ballot(pc);
    if (lane == 0) { s_wn[wave] = __popcll(mn); s_wc[wave] = __popcll(mc); }
    __syncthreads();

    int bn = 0, bc = 0, ncnt = 0, ccnt = 0;
    #pragma unroll
    for (int w = 0; w < WAVES; ++w) {
        int pw = s_wn[w], cw = s_wc[w];
        if (w < wave) { bn += pw; bc += cw; }
        ncnt += pw; ccnt += cw;
    }
    const int lo = GG - ccnt;
    int nc_eff = (ncnt + 3) & ~3;          // pad nc list up to x4
    int lo_pad = lo & ~3;                  // pad crowd list down to x4
    if (nc_eff > lo_pad) nc_eff = lo_pad;

    {
        const unsigned long long lt = (1ULL << lane) - 1ULL;
        if (pn) {
            int idx = bn + __popcll(mn & lt);
            s_box[idx]  = box;
            s_area[idx] = (box.z - box.x) * (box.w - box.y);
        }
        if (pc) {
            int idx = (GG - 1) - (bc + __popcll(mc & lt));
            s_box[idx]  = box;
            s_area[idx] = (box.z - box.x) * (box.w - box.y);
        }
        // zero-fill pad slots (zero box => t=0, harmless for max)
        const float4 z = make_float4(0.f, 0.f, 0.f, 0.f);
        if (tid < 4) {
            int i = ncnt + tid;
            if (i < nc_eff) { s_box[i] = z; s_area[i] = 0.f; }
        } else if (tid < 8) {
            int i = lo_pad + (tid - 4);
            if (i < lo) { s_box[i] = z; s_area[i] = 0.f; }
        }
    }
    __syncthreads();

    // t = inter * rcp(rarea + garea + eps)  (monotone in IoU)
    auto tval = [](const float4& rr, float rsum, const float4& g4, float ga) -> float {
        float dy = fminf(rr.z, g4.z) - fmaxf(rr.x, g4.x);
        float dx = fminf(rr.w, g4.w) - fmaxf(rr.y, g4.y);
        float inter = fmaxf(fmaxf(dy, 0.f) * dx, 0.f);
        return inter * __builtin_amdgcn_rcpf(rsum + ga);
    };

    float anc[RPT] = {0.f, 0.f};
    float ac[RPT]  = {0.f, 0.f};

    // Software-pipelined group loop: load group q+1 while computing group q.
    auto run = [&](int q0, int q1, float* acc) {
        if (q0 >= q1) return;
        float4 nb0 = s_box[4 * q0 + 0];
        float4 nb1 = s_box[4 * q0 + 1];
        float4 nb2 = s_box[4 * q0 + 2];
        float4 nb3 = s_box[4 * q0 + 3];
        float4 na  = s_area4[q0];
        #pragma unroll 2
        for (int q = q0; q < q1; ++q) {
            const float4 cb0 = nb0, cb1 = nb1, cb2 = nb2, cb3 = nb3, ca = na;
            const int qn = (q + 1 < q1) ? q + 1 : q0;     // wrap: last prefetch unused
            nb0 = s_box[4 * qn + 0];
            nb1 = s_box[4 * qn + 1];
            nb2 = s_box[4 * qn + 2];
            nb3 = s_box[4 * qn + 3];
            na  = s_area4[qn];
            #pragma unroll
            for (int i = 0; i < RPT; ++i) {
                float t0 = tval(r[i], rs[i], cb0, ca.x);
                float t1 = tval(r[i], rs[i], cb1, ca.y);
                float t2 = tval(r[i], rs[i], cb2, ca.z);
                float t3 = tval(r[i], rs[i], cb3, ca.w);
                acc[i] = fmaxf(acc[i], fmaxf(fmaxf(t0, t1), fmaxf(t2, t3)));
            }
        }
    };

    // ---- non-crowd: groups [0, nc_eff/4), split across 8 waves ----
    {
        const int ngr = nc_eff >> 2;
        const int gpw = (ngr + WAVES - 1) / WAVES;
        const int q0 = rfl(wave * gpw);
        const int q1 = rfl(min(ngr, q0 + gpw));
        run(q0, q1, anc);
    }
    // ---- crowd: groups [lo_pad/4, GG/4), split across 8 waves ----
    {
        const int cg0 = lo_pad >> 2;
        const int cgn = (GG >> 2) - cg0;
        const int gpw = (cgn + WAVES - 1) / WAVES;
        const int q0 = rfl(cg0 + wave * gpw);
        const int q1 = rfl(min(GG >> 2, q0 + gpw));
        run(q0, q1, ac);
    }

    #pragma unroll
    for (int i = 0; i < RPT; ++i) {
        s_ncm[wave][i * 64 + lane] = anc[i];
        s_cm[wave][i * 64 + lane]  = ac[i];
    }
    __syncthreads();

    // ---- reduce across waves; threads 0..RPB-1 own one ROI slot each ----
    // Slot tid corresponds to this thread's own r[tid>>6] (wave 0 -> r[0], wave 1 -> r[1]).
    if (tid < RPB) {
        const int n = nbase + tid;
        if (n < NN) {
            float a = s_ncm[0][tid], c = s_cm[0][tid];
            #pragma unroll
            for (int w = 1; w < WAVES; ++w) {
                a = fmaxf(a, s_ncm[w][tid]);
                c = fmaxf(c, s_cm[w][tid]);
            }
            const float4 rr = (tid < 64) ? r[0] : r[1];
            const float vr =
                ((fabsf(rr.x) + fabsf(rr.y) + fabsf(rr.z) + fabsf(rr.w)) > 0.f) ? 1.f : 0.f;
            a *= vr;
            c *= vr;
            // t -> iou: iou = t/(1-t); t in [0, 0.5] so well-conditioned
            const float nc_max = a * __builtin_amdgcn_rcpf(1.f - a);
            const float c_max  = c * __builtin_amdgcn_rcpf(1.f - c);

            out[b * 2 * NN + n]      = nc_max;     // iou_maxes (B,2,N) ch0
            out[b * 2 * NN + NN + n] = c_max;      // iou_maxes (B,2,N) ch1
            const float pos = (vr > 0.f && nc_max >= 0.5f) ? 1.0f : 0.0f;
            const float neg = (vr > 0.f && nc_max < 0.5f && c_max < 0.001f) ? 1.0f : 0.0f;
            out[BB * 2 * NN + b * NN + n]           = pos;
            out[BB * 2 * NN + BB * NN + b * NN + n] = neg;
        }
    }
}

extern "C" void kernel_launch(void* const* d_in, const int* in_sizes, int n_in,
                              void* d_out, int out_size, void* d_ws, size_t ws_size,
                              hipStream_t stream) {
    const float4* rois     = (const float4*)d_in[0];
    const int*    gt_ids   = (const int*)d_in[1];
    const float4* gt_boxes = (const float4*)d_in[2];
    float*        out      = (float*)d_out;

    dim3 grid((NN + RPB - 1) / RPB, BB);   // 47 x 16 = 752 blocks, 8 waves each
    det_kernel<<<grid, 64 * WAVES, 0, stream>>>(rois, gt_ids, gt_boxes, out);
}

// Round 15
// 24.161 us; speedup vs baseline: 1.0675x; 1.0379x over previous
//
#include <hip/hip_runtime.h>

#define BB 16
#define NN 6000
#define GG 512
#define WAVES 8
#define RPT 3
#define RPB (RPT * 64)   // 192 ROIs/block; grid.x = 32 -> 512 blocks = 2/CU

__device__ __forceinline__ int rfl(int v) { return __builtin_amdgcn_readfirstlane(v); }
__device__ __forceinline__ float2 min2s(float2 a, float s) { return make_float2(fminf(a.x, s), fminf(a.y, s)); }
__device__ __forceinline__ float2 max2s(float2 a, float s) { return make_float2(fmaxf(a.x, s), fmaxf(a.y, s)); }

__global__ __launch_bounds__(64 * WAVES) void det_kernel(
    const float4* __restrict__ rois,      // (B, N, 4)
    const int*    __restrict__ gt_ids,    // (B, G)
    const float4* __restrict__ gt_boxes,  // (B, G, 4)
    float*        __restrict__ out)       // [B*2*N maxes][B*N pos][B*N neg]
{
    __shared__ float4 s_box[GG];             // nc from front, crowd from back
    __shared__ float  s_ncm[WAVES][RPB];
    __shared__ float  s_cm[WAVES][RPB];
    __shared__ float  s_val[RPB];
    __shared__ int    s_wn[WAVES], s_wc[WAVES];   // per-wave popcounts

    const int b    = blockIdx.y;
    const int tid  = threadIdx.x;
    const int wave = tid >> 6;
    const int lane = tid & 63;

    // ---- issue all global loads first ----
    const int nbase = blockIdx.x * RPB;
    float4 r[RPT];
    #pragma unroll
    for (int i = 0; i < RPT; ++i) {
        int n = nbase + i * 64 + lane;
        r[i] = (n < NN) ? rois[b * NN + n] : make_float4(0.f, 0.f, 0.f, 0.f);
    }
    const float4 box = gt_boxes[b * GG + tid];    // one GT per thread (512 == GG)
    const int    id  = gt_ids[b * GG + tid];

    float rsv[RPT];
    #pragma unroll
    for (int i = 0; i < RPT; ++i) {
        rsv[i] = (r[i].z - r[i].x) * (r[i].w - r[i].y) + 1e-8f;
        if (wave == 0)
            s_val[i * 64 + lane] =
                ((fabsf(r[i].x) + fabsf(r[i].y) + fabsf(r[i].z) + fabsf(r[i].w)) > 0.f) ? 1.f : 0.f;
    }

    // ---- ballot compaction, atomic-free (per-wave prefix) ----
    const float asum = fabsf(box.x) + fabsf(box.y) + fabsf(box.z) + fabsf(box.w);
    const bool pn = (asum > 0.0f) && (id > 0);
    const bool pc = (asum > 0.0f) && (id < 0);
    const unsigned long long mn = __ballot(pn);
    const unsigned long long mc = __ballot(pc);
    if (lane == 0) { s_wn[wave] = __popcll(mn); s_wc[wave] = __popcll(mc); }
    __syncthreads();

    int bn = 0, bc = 0, ncnt = 0, ccnt = 0;
    #pragma unroll
    for (int w = 0; w < WAVES; ++w) {
        int pw = s_wn[w], cw = s_wc[w];
        if (w < wave) { bn += pw; bc += cw; }
        ncnt += pw; ccnt += cw;
    }
    const int lo = GG - ccnt;
    int nc_eff = (ncnt + 3) & ~3;          // pad nc list up to x4
    int lo_pad = lo & ~3;                  // pad crowd list down to x4
    if (nc_eff > lo_pad) nc_eff = lo_pad;

    {
        const unsigned long long lt = (1ULL << lane) - 1ULL;
        if (pn) s_box[bn + __popcll(mn & lt)] = box;
        if (pc) s_box[(GG - 1) - (bc + __popcll(mc & lt))] = box;
        // zero-fill pad slots (zero box => t=0, harmless for max)
        const float4 z = make_float4(0.f, 0.f, 0.f, 0.f);
        if (tid < 4) {
            int i = ncnt + tid;
            if (i < nc_eff) s_box[i] = z;
        } else if (tid < 8) {
            int i = lo_pad + (tid - 4);
            if (i < lo) s_box[i] = z;
        }
    }
    __syncthreads();

    // Packed-ROI constants: ROIs 0,1 as float2 lanes; ROI 2 scalar.
    const float2 ry1c = make_float2(r[0].x, r[1].x);
    const float2 rx1c = make_float2(r[0].y, r[1].y);
    const float2 ry2c = make_float2(r[0].z, r[1].z);
    const float2 rx2c = make_float2(r[0].w, r[1].w);
    const float2 rs01 = make_float2(rsv[0], rsv[1]);
    const float4 r2   = r[2];
    const float  rs2  = rsv[2];

    // t for ROI duo (packed arith: subs/muls -> v_pk_*_f32) and ROI 2 (scalar)
    auto tduo = [&](const float4& g4, float ga) -> float2 {
        float2 dy = min2s(ry2c, g4.z) - max2s(ry1c, g4.x);
        float2 dx = min2s(rx2c, g4.w) - max2s(rx1c, g4.y);
        float2 p  = max2s(dy, 0.f) * dx;
        float2 it = max2s(p, 0.f);
        return make_float2(it.x * __builtin_amdgcn_rcpf(rs01.x + ga),
                           it.y * __builtin_amdgcn_rcpf(rs01.y + ga));
    };
    auto tsc = [&](const float4& g4, float ga) -> float {
        float dy = fminf(r2.z, g4.z) - fmaxf(r2.x, g4.x);
        float dx = fminf(r2.w, g4.w) - fmaxf(r2.y, g4.y);
        float it = fmaxf(fmaxf(dy, 0.f) * dx, 0.f);
        return it * __builtin_amdgcn_rcpf(rs2 + ga);
    };

    float2 a01n = make_float2(0.f, 0.f), a01c = make_float2(0.f, 0.f);
    float  a2n = 0.f, a2c = 0.f;

    // Software-pipelined group loop: load group q+1 while computing group q.
    auto run = [&](int q0, int q1, float2& acc2, float& acc1) {
        if (q0 >= q1) return;
        float4 nb0 = s_box[4 * q0 + 0];
        float4 nb1 = s_box[4 * q0 + 1];
        float4 nb2 = s_box[4 * q0 + 2];
        float4 nb3 = s_box[4 * q0 + 3];
        #pragma unroll 2
        for (int q = q0; q < q1; ++q) {
            const float4 cb0 = nb0, cb1 = nb1, cb2 = nb2, cb3 = nb3;
            const int qn = (q + 1 < q1) ? q + 1 : q0;     // wrap: last prefetch unused
            nb0 = s_box[4 * qn + 0];
            nb1 = s_box[4 * qn + 1];
            nb2 = s_box[4 * qn + 2];
            nb3 = s_box[4 * qn + 3];
            const float ga0 = (cb0.z - cb0.x) * (cb0.w - cb0.y);
            const float ga1 = (cb1.z - cb1.x) * (cb1.w - cb1.y);
            const float ga2 = (cb2.z - cb2.x) * (cb2.w - cb2.y);
            const float ga3 = (cb3.z - cb3.x) * (cb3.w - cb3.y);
            float2 t0 = tduo(cb0, ga0);
            float2 t1 = tduo(cb1, ga1);
            float2 t2 = tduo(cb2, ga2);
            float2 t3 = tduo(cb3, ga3);
            // v_max3 chains
            acc2.x = fmaxf(fmaxf(fmaxf(fmaxf(t0.x, t1.x), t2.x), t3.x), acc2.x);
            acc2.y = fmaxf(fmaxf(fmaxf(fmaxf(t0.y, t1.y), t2.y), t3.y), acc2.y);
            float u0 = tsc(cb0, ga0);
            float u1 = tsc(cb1, ga1);
            float u2 = tsc(cb2, ga2);
            float u3 = tsc(cb3, ga3);
            acc1 = fmaxf(fmaxf(fmaxf(fmaxf(u0, u1), u2), u3), acc1);
        }
    };

    // ---- non-crowd: groups [0, nc_eff/4), split across 8 waves ----
    {
        const int ngr = nc_eff >> 2;
        const int gpw = (ngr + WAVES - 1) / WAVES;
        const int q0 = rfl(wave * gpw);
        const int q1 = rfl(min(ngr, q0 + gpw));
        run(q0, q1, a01n, a2n);
    }
    // ---- crowd: groups [lo_pad/4, GG/4), split across 8 waves ----
    {
        const int cg0 = lo_pad >> 2;
        const int cgn = (GG >> 2) - cg0;
        const int gpw = (cgn + WAVES - 1) / WAVES;
        const int q0 = rfl(cg0 + wave * gpw);
        const int q1 = rfl(min(GG >> 2, q0 + gpw));
        run(q0, q1, a01c, a2c);
    }

    s_ncm[wave][lane]       = a01n.x;
    s_ncm[wave][64 + lane]  = a01n.y;
    s_ncm[wave][128 + lane] = a2n;
    s_cm[wave][lane]        = a01c.x;
    s_cm[wave][64 + lane]   = a01c.y;
    s_cm[wave][128 + lane]  = a2c;
    __syncthreads();

    // ---- reduce across waves; threads 0..RPB-1 own one ROI slot each ----
    if (tid < RPB) {
        const int n = nbase + tid;
        if (n < NN) {
            float a = s_ncm[0][tid], c = s_cm[0][tid];
            #pragma unroll
            for (int w = 1; w < WAVES; ++w) {
                a = fmaxf(a, s_ncm[w][tid]);
                c = fmaxf(c, s_cm[w][tid]);
            }
            const float vr = s_val[tid];           // 1.0 or 0.0
            a *= vr;
            c *= vr;
            // t -> iou: iou = t/(1-t); t in [0, 0.5] so well-conditioned
            const float nc_max = a * __builtin_amdgcn_rcpf(1.f - a);
            const float c_max  = c * __builtin_amdgcn_rcpf(1.f - c);

            out[b * 2 * NN + n]      = nc_max;     // iou_maxes (B,2,N) ch0
            out[b * 2 * NN + NN + n] = c_max;      // iou_maxes (B,2,N) ch1
            const float pos = (vr > 0.f && nc_max >= 0.5f) ? 1.0f : 0.0f;
            const float neg = (vr > 0.f && nc_max < 0.5f && c_max < 0.001f) ? 1.0f : 0.0f;
            out[BB * 2 * NN + b * NN + n]           = pos;
            out[BB * 2 * NN + BB * NN + b * NN + n] = neg;
        }
    }
}

extern "C" void kernel_launch(void* const* d_in, const int* in_sizes, int n_in,
                              void* d_out, int out_size, void* d_ws, size_t ws_size,
                              hipStream_t stream) {
    const float4* rois     = (const float4*)d_in[0];
    const int*    gt_ids   = (const int*)d_in[1];
    const float4* gt_boxes = (const float4*)d_in[2];
    float*        out      = (float*)d_out;

    dim3 grid((NN + RPB - 1) / RPB, BB);   // 32 x 16 = 512 blocks = exactly 2/CU
    det_kernel<<<grid, 64 * WAVES, 0, stream>>>(rois, gt_ids, gt_boxes, out);
}